// Round 10
// baseline (10235.192 us; speedup 1.0000x reference)
//
#include <hip/hip_runtime.h>
#include <hip/hip_bf16.h>

typedef _Float16 f16;
typedef _Float16 f16x8 __attribute__((ext_vector_type(8)));
typedef float f32x4 __attribute__((ext_vector_type(4)));

#define T_ 256
#define SC 2048.0f
#define INV_SC (1.0f / 2048.0f)
#define RMASK 15          // 16-slot rings for recurrent h buffers
#define MFMA(A, B, C) __builtin_amdgcn_mfma_f32_16x16x32_f16(A, B, C, 0, 0, 0)

// ---------------------------------------------------------------------------
// A-buffers (x or h frags): [mt 4][ks 32][part 2][lane 64][e 8] f16 (256 KB/step)
// W pack per layer: [which 2 (hi/lo*SC)][jb 128][nt 2][ks 64][lane 64][e 8] f16
//   row n' = jb*32 + nt*16 + (l&15); k = ks*32+(l>>4)*8+e over [xr|xi|hr|hi]
// Numerics = round-8 exact (f16 hi + a_lo & W_lo compensation, fp32 cell).
// NEW: per-mt (batch-quarter) decoupled pipelines — batch rows are independent
// recurrences, so the 4 mt-groups sync independently (LDS ctr + per-group flags).
// ---------------------------------------------------------------------------

__global__ void prepack_x_kernel(const float* __restrict__ x, f16* __restrict__ X0) {
  unsigned int idx = blockIdx.x * 256 + threadIdx.x;  // < 33,554,432
  int e    = idx & 7;
  int l    = (idx >> 3) & 63;
  int part = (idx >> 9) & 1;
  int ks   = (idx >> 10) & 31;
  int mt   = (idx >> 15) & 3;
  int t    = idx >> 17;
  int m = mt * 16 + (l & 15);
  int k = ks * 32 + ((l >> 4) << 3) + e;
  int cc = k >> 9, kw = k & 511;
  float v = x[(((size_t)m * T_ + t) * 512 + kw) * 2 + cc];
  f16 h = (f16)v;
  X0[idx] = part ? (f16)((v - (float)h) * SC) : h;
}

// 16,777,216 threads exactly (grid 65536 x 256): hi plane + lo plane.
__global__ void prepack_w_kernel(const float* __restrict__ Wri, const float* __restrict__ Wii,
                                 const float* __restrict__ Wrh, const float* __restrict__ Wih,
                                 f16* __restrict__ out) {
  unsigned int idx = blockIdx.x * 256 + threadIdx.x;  // < 16,777,216
  int e     = idx & 7;
  int l     = (idx >> 3) & 63;
  int ks    = (idx >> 9) & 63;
  int nt    = (idx >> 15) & 1;
  int jb    = (idx >> 16) & 127;
  int which = idx >> 23;
  int n_local = nt * 16 + (l & 15);
  int np = jb * 32 + n_local;
  int j  = np >> 3;
  int g  = (np >> 1) & 3;
  int cc = np & 1;
  int k  = ks * 32 + ((l >> 4) << 3) + e;
  int kb = k >> 9, kw = k & 511;
  size_t s = (size_t)(g * 512 + j) * 512 + kw;
  float v;
  if (cc == 0) v = (kb == 0) ? Wri[s] : (kb == 1) ? -Wii[s] : (kb == 2) ? Wrh[s] : -Wih[s];
  else         v = (kb == 0) ? Wii[s] : (kb == 1) ?  Wri[s] : (kb == 2) ? Wih[s] :  Wrh[s];
  f16 h = (f16)v;
  out[idx] = which ? (f16)((v - (float)h) * SC) : h;
}

struct PersistArgs {
  const f16* X0;      // [T][131072] layer-0 x frags
  f16* ys0;           // 16-slot ring: layer-0 h frags (= layer-1 x input)
  f16* h1;            // 16-slot ring: layer-1 h frags
  const f16* Wpk0;    // [2][128][65536] (hi | lo)
  const f16* Wpk1;
  const float *br10, *bi10, *br20, *bi20;
  const float *br11, *bi11, *br21, *bi21;
  float* y;           // (B,T,512,2)
  float* hout;        // (2,B,512,2)
  float* cout;        // (2,B,512,2)
  unsigned* flags;    // [4][256] per (mt-group, block)
};

__device__ __forceinline__ void lds_wait(unsigned* p, unsigned target) {
  while (__hip_atomic_load(p, __ATOMIC_ACQUIRE, __HIP_MEMORY_SCOPE_WORKGROUP) < target)
    __builtin_amdgcn_s_sleep(1);
}
__device__ __forceinline__ void lds_signal(unsigned* p, int lane) {
  if (lane == 0)
    __hip_atomic_fetch_add(p, 1u, __ATOMIC_RELEASE, __HIP_MEMORY_SCOPE_WORKGROUP);
}

// 256 blocks x 1024 threads; 128 blocks/layer, 4 hidden j each.
// Wave w: group g = w>>2 (batch quarter), kq = w&3 (kq0/1 = x-K, kq2/3 = h-K).
// Per-group 5-phase ctr protocol per stage: writers(kq0,2)@5s, adders(kq1,3)@5s+2,
// epilogue(kq0)@5s+4 -> 5s+5. No __syncthreads in the stage loop.
__global__ __launch_bounds__(1024, 4) void lstm_persist(PersistArgs a) {
  extern __shared__ char smem[];
  f16* Wl = (f16*)smem;                       // W-hi slice 131072 B
  float* redf = (float*)(smem + 131072);      // [4 g][2 pair][2 nt][16][17] = 17408 B
  unsigned* ctr = (unsigned*)(smem + 148480); // [4]

  int bid = blockIdx.x;
  int xcd = bid & 7, rr = bid >> 3;
  int lay = rr & 1;
  int jb = (rr >> 1) * 8 + xcd;       // 0..127
  int tid = threadIdx.x;
  int w = tid >> 6, l = tid & 63;
  int g = w >> 2, kq = w & 3;
  int n_loc = l & 15, r0 = (l >> 4) * 4;
  bool xwave = (kq < 2);

  // epilogue identity (kq0 lanes): one (m, j-local) pair
  int eml = l >> 2, ejl = l & 3;
  int mG = g * 16 + eml;
  int jg = jb * 4 + ejl;

  const f16* Wpk = lay ? a.Wpk1 : a.Wpk0;
  const f16* WhiG = Wpk + (size_t)jb * 65536;
  const f16* WloG = Wpk + 8388608 + (size_t)jb * 65536;
  for (int i = tid * 8; i < 65536; i += 8192)
    *reinterpret_cast<f16x8*>(Wl + i) = *reinterpret_cast<const f16x8*>(WhiG + i);
  if (tid < 4) ctr[tid] = 0u;

  float bsr[4], bsi[4];
  {
    const float* br1 = lay ? a.br11 : a.br10;
    const float* bi1 = lay ? a.bi11 : a.bi10;
    const float* br2 = lay ? a.br21 : a.br20;
    const float* bi2 = lay ? a.bi21 : a.bi20;
#pragma unroll
    for (int q = 0; q < 4; ++q) {
      int nb = q * 512 + jg;
      bsr[q] = br1[nb] + br2[nb];
      bsi[q] = bi1[nb] + bi2[nb];
    }
  }
  __syncthreads();   // Wl + ctr ready (only block-wide barrier in the kernel)

  float c_r = 0.f, c_i = 0.f;

  for (int s = 0; s <= T_; ++s) {
    bool active = lay ? (s >= 1) : (s < T_);
    int t = lay ? (s - 1) : s;
    unsigned base = 5u * (unsigned)s;

    // ---- global poll (per wave, per group): need all blocks' group g >= s ----
    bool needPoll = active && (xwave ? (lay == 1 && s > 0) : (t > 0));
    if (needPoll) {
      const unsigned* fp = a.flags + g * 256 + l * 4;
      for (;;) {
        unsigned f0 = __hip_atomic_load(fp + 0, __ATOMIC_RELAXED, __HIP_MEMORY_SCOPE_AGENT);
        unsigned f1 = __hip_atomic_load(fp + 1, __ATOMIC_RELAXED, __HIP_MEMORY_SCOPE_AGENT);
        unsigned f2 = __hip_atomic_load(fp + 2, __ATOMIC_RELAXED, __HIP_MEMORY_SCOPE_AGENT);
        unsigned f3 = __hip_atomic_load(fp + 3, __ATOMIC_RELAXED, __HIP_MEMORY_SCOPE_AGENT);
        unsigned mn = min(min(f0, f1), min(f2, f3));
        if (__all(mn >= (unsigned)s)) break;
        __builtin_amdgcn_s_sleep(1);
      }
      asm volatile("" ::: "memory");
    }

    // ---- GEMM (this wave's K-quarter, both n-tiles) ----
    f32x4 acc0 = {0,0,0,0}, acc1 = {0,0,0,0}, sacc0 = {0,0,0,0}, sacc1 = {0,0,0,0};
    bool doGemm = active && (xwave || t > 0);
    if (doGemm) {
      const f16* Ab;
      if (xwave)
        Ab = lay ? (a.ys0 + (size_t)(t & RMASK) * 131072)
                 : (a.X0 + (size_t)t * 131072);
      else
        Ab = (lay ? a.h1 : a.ys0) + (size_t)((t - 1) & RMASK) * 131072;
      const f16* pa = Ab + g * 32768 + (kq & 1) * 16384 + l * 8;
      const f16* pw = Wl + kq * 8192 + l * 8;
      const f16* po = WloG + kq * 8192 + l * 8;
#pragma unroll 4
      for (int i = 0; i < 16; ++i) {
        f16x8 ah = *reinterpret_cast<const f16x8*>(pa + i * 1024);
        f16x8 al = *reinterpret_cast<const f16x8*>(pa + i * 1024 + 512);
        f16x8 w0 = *reinterpret_cast<const f16x8*>(pw + i * 512);
        f16x8 w1 = *reinterpret_cast<const f16x8*>(pw + 32768 + i * 512);
        f16x8 o0 = *reinterpret_cast<const f16x8*>(po + i * 512);
        f16x8 o1 = *reinterpret_cast<const f16x8*>(po + 32768 + i * 512);
        acc0 = MFMA(ah, w0, acc0); sacc0 = MFMA(al, w0, sacc0); sacc0 = MFMA(ah, o0, sacc0);
        acc1 = MFMA(ah, w1, acc1); sacc1 = MFMA(al, w1, sacc1); sacc1 = MFMA(ah, o1, sacc1);
      }
    }
    f32x4 comb0 = acc0 + sacc0 * INV_SC;
    f32x4 comb1 = acc1 + sacc1 * INV_SC;

    // ---- per-group reduce via ctr protocol ----
    int rb0 = ((g * 2 + (kq >> 1)) * 2 + 0) * 272 + n_loc * 17 + r0;
    int rb1 = rb0 + 272;
    if ((kq & 1) == 0) {            // writers: kq0 (x-pair), kq2 (h-pair)
      lds_wait(&ctr[g], base);      // prev-stage epilogue consumed redf
#pragma unroll
      for (int q = 0; q < 4; ++q) { redf[rb0 + q] = comb0[q]; redf[rb1 + q] = comb1[q]; }
      lds_signal(&ctr[g], l);       // -> 5s+2 (with the other writer)
    } else {                        // adders: kq1, kq3
      lds_wait(&ctr[g], base + 2);
#pragma unroll
      for (int q = 0; q < 4; ++q) { redf[rb0 + q] += comb0[q]; redf[rb1 + q] += comb1[q]; }
      lds_signal(&ctr[g], l);       // -> 5s+4
    }

    // ---- epilogue: kq0 wave only ----
    if (kq == 0) {
      lds_wait(&ctr[g], base + 4);
      float hr = 0.f, him = 0.f, cnr = 0.f, cni = 0.f;
      float zr[4], zi[4];
      if (active) {
#pragma unroll
        for (int q = 0; q < 4; ++q) {
          int nl = ejl * 8 + q * 2;
          int nt_ = nl >> 4, nn = nl & 15;
          int i0 = ((g * 2 + 0) * 2 + nt_) * 272 + nn * 17 + eml;
          int i1 = ((g * 2 + 1) * 2 + nt_) * 272 + nn * 17 + eml;
          zr[q] = redf[i0] + redf[i1] + bsr[q];
          zi[q] = redf[i0 + 17] + redf[i1 + 17] + bsi[q];
        }
      }
      lds_signal(&ctr[g], l);       // redf consumed -> 5(s+1)
      if (active) {
        float gr[4], gi[4];
#pragma unroll
        for (int q = 0; q < 4; ++q) {
          float mag = sqrtf(zr[q] * zr[q] + zi[q] * zi[q]);
          float fn = (q < 3) ? (1.f / (1.f + __expf(-mag))) : tanhf(mag);
          float sg = fn / (mag + 1e-8f);
          gr[q] = zr[q] * sg;
          gi[q] = zi[q] * sg;
        }
        cnr = c_r * gr[1] + gr[0] * gr[3];
        cni = c_i * gi[1] + gi[0] * gi[3];
        c_r = cnr; c_i = cni;
        float mm = sqrtf(cnr * cnr + cni * cni);
        float sg = tanhf(mm) / (mm + 1e-8f);
        float dr = cnr * sg, di = cni * sg;
        hr  = gr[2] * dr - gi[2] * di;
        him = gi[2] * dr + gr[2] * di;

        // pack h-frags pairwise (j, j^1): 2 u32 MALL stores per lane
        f16 h0 = (f16)hr, h2 = (f16)him;
        unsigned a1 = (unsigned)__builtin_bit_cast(unsigned short, h0)
                    | ((unsigned)__builtin_bit_cast(unsigned short, (f16)((hr - (float)h0) * SC)) << 16);
        unsigned a2 = (unsigned)__builtin_bit_cast(unsigned short, h2)
                    | ((unsigned)__builtin_bit_cast(unsigned short, (f16)((him - (float)h2) * SC)) << 16);
        unsigned b1 = __shfl_xor(a1, 1, 64);
        unsigned b2 = __shfl_xor(a2, 1, 64);
        unsigned v0, v1; int kbase;
        int p = ejl >> 1;
        if ((ejl & 1) == 0) {
          v0 = (a1 & 0xffffu) | (b1 << 16);
          v1 = (a1 >> 16) | (b1 & 0xffff0000u);
          kbase = jb * 4 + 2 * p;               // real planes
        } else {
          v0 = (b2 & 0xffffu) | (a2 << 16);
          v1 = (b2 >> 16) | (a2 & 0xffff0000u);
          kbase = 512 + jb * 4 + 2 * p;         // imag planes
        }
        f16* Yb = (lay ? a.h1 : a.ys0) + (size_t)(t & RMASK) * 131072;
        unsigned* Y32 = (unsigned*)Yb;
        int ks2 = kbase >> 5;
        int lane_h = eml + 16 * ((kbase >> 3) & 3);
        int e0 = kbase & 7;
        int idx0 = ((g * 32 + ks2) * 2 + 0) * 512 + lane_h * 8 + e0;
        int idx1 = ((g * 32 + ks2) * 2 + 1) * 512 + lane_h * 8 + e0;
        __hip_atomic_store(&Y32[idx0 >> 1], v0, __ATOMIC_RELAXED, __HIP_MEMORY_SCOPE_AGENT);
        __hip_atomic_store(&Y32[idx1 >> 1], v1, __ATOMIC_RELAXED, __HIP_MEMORY_SCOPE_AGENT);
      }
      asm volatile("s_waitcnt vmcnt(0)" ::: "memory");  // drain this wave's h-stores
      if (l == 0 && s < T_)
        __hip_atomic_store(&a.flags[g * 256 + bid], (unsigned)(s + 1),
                           __ATOMIC_RELAXED, __HIP_MEMORY_SCOPE_AGENT);
      // deferred fp32 outputs — off the flag path
      if (active) {
        if (lay) {
          float2 yv; yv.x = hr; yv.y = him;
          *reinterpret_cast<float2*>(a.y + (((size_t)mG * T_ + t) * 512 + jg) * 2) = yv;
        }
        if (t == T_ - 1) {
          float* hp = a.hout + (size_t)lay * 65536 + ((size_t)mG * 512 + jg) * 2;
          hp[0] = hr; hp[1] = him;
          float* cq = a.cout + (size_t)lay * 65536 + ((size_t)mG * 512 + jg) * 2;
          cq[0] = cnr; cq[1] = cni;
        }
      }
    }
  }
}

extern "C" void kernel_launch(void* const* d_in, const int* in_sizes, int n_in,
                              void* d_out, int out_size, void* d_ws, size_t ws_size,
                              hipStream_t stream) {
  const float* x = (const float*)d_in[0];
  char* ws = (char*)d_ws;
  f16* X0   = (f16*)(ws + 0);                          //  64 MB
  f16* Wpk0 = (f16*)(ws + (size_t)67108864);           //  32 MB (hi|lo)
  f16* Wpk1 = (f16*)(ws + (size_t)100663296);          //  32 MB
  f16* ys0  = (f16*)(ws + (size_t)134217728);          //   4 MB ring
  f16* h1   = (f16*)(ws + (size_t)138412032);          //   4 MB ring
  unsigned* flags = (unsigned*)(ws + (size_t)142606336);  // 4 KB [4][256]

  hipMemsetAsync(ws + 142606336, 0, 4096, stream);

  prepack_x_kernel<<<131072, 256, 0, stream>>>(x, X0);
  prepack_w_kernel<<<65536, 256, 0, stream>>>((const float*)d_in[1], (const float*)d_in[2],
                                              (const float*)d_in[5], (const float*)d_in[6], Wpk0);
  prepack_w_kernel<<<65536, 256, 0, stream>>>((const float*)d_in[9], (const float*)d_in[10],
                                              (const float*)d_in[13], (const float*)d_in[14], Wpk1);

  float* y = (float*)d_out;
  PersistArgs pa;
  pa.X0 = X0; pa.ys0 = ys0; pa.h1 = h1;
  pa.Wpk0 = Wpk0; pa.Wpk1 = Wpk1;
  pa.br10 = (const float*)d_in[3];  pa.bi10 = (const float*)d_in[4];
  pa.br20 = (const float*)d_in[7];  pa.bi20 = (const float*)d_in[8];
  pa.br11 = (const float*)d_in[11]; pa.bi11 = (const float*)d_in[12];
  pa.br21 = (const float*)d_in[15]; pa.bi21 = (const float*)d_in[16];
  pa.y = y; pa.hout = y + 16777216; pa.cout = y + 16777216 + 131072;
  pa.flags = flags;

  hipFuncSetAttribute((const void*)lstm_persist,
                      hipFuncAttributeMaxDynamicSharedMemorySize, 148608);
  void* kargs[] = { &pa };
  hipLaunchCooperativeKernel((const void*)lstm_persist, dim3(256), dim3(1024),
                             kargs, 148608, stream);
}

// Round 11
// 4535.306 us; speedup vs baseline: 2.2568x; 2.2568x over previous
//
#include <hip/hip_runtime.h>
#include <hip/hip_bf16.h>

typedef _Float16 f16;
typedef _Float16 f16x8 __attribute__((ext_vector_type(8)));
typedef float f32x4 __attribute__((ext_vector_type(4)));
typedef unsigned char u8;

#define T_ 256
#define SC 2048.0f
#define INV_SC (1.0f / 2048.0f)
#define RMASK 15          // 16-slot rings for recurrent h buffers
#define MFMA(A, B, C)  __builtin_amdgcn_mfma_f32_16x16x32_f16(A, B, C, 0, 0, 0)
#define MFMA8(A, B, C) __builtin_amdgcn_mfma_f32_16x16x32_fp8_fp8(A, B, C, 0, 0, 0)

__device__ __forceinline__ u8 f2fp8(float v) {
  int r = __builtin_amdgcn_cvt_pk_fp8_f32(v, 0.f, 0, false);
  return (u8)(r & 0xff);
}

// ---------------------------------------------------------------------------
// Structure = round 8 (4.16ms known-good): 256 blocks x 1024 thr, 128 blocks
// per layer (lay=(bid>>3)&1), 4 hidden j per block, layer-wavefront stages.
// CHANGE vs round 8: W-lo compensation plane is fp8 e4m3 (8MB/layer, L2-resident)
// fed to mfma_f32_16x16x32_fp8_fp8 against an fp8 hi-plane of A.
//   A f16  (x or h): [mt 4][ks 32][part 2][lane 64][e 8] f16 (256 KB/step)
//   A fp8 hi-plane:  [mt 4][ks 32][lane 64][e 8] bytes      (64 KB/step)
//   W hi  f16: [jb 128][nt 2][ks 64][lane 64][e 8]          (16 MB/layer, LDS)
//   W lo8 fp8: same index, bytes, value = (W - f16(W))*SC    (8 MB/layer, L2)
// fp8 A/B frags share the same e-order => internal byte->k mapping cancels.
// ---------------------------------------------------------------------------

__global__ void prepack_x_kernel(const float* __restrict__ x, f16* __restrict__ X0) {
  unsigned int idx = blockIdx.x * 256 + threadIdx.x;  // < 33,554,432
  int e    = idx & 7;
  int l    = (idx >> 3) & 63;
  int part = (idx >> 9) & 1;
  int ks   = (idx >> 10) & 31;
  int mt   = (idx >> 15) & 3;
  int t    = idx >> 17;
  int m = mt * 16 + (l & 15);
  int k = ks * 32 + ((l >> 4) << 3) + e;
  int cc = k >> 9, kw = k & 511;
  float v = x[(((size_t)m * T_ + t) * 512 + kw) * 2 + cc];
  f16 h = (f16)v;
  X0[idx] = part ? (f16)((v - (float)h) * SC) : h;
}

// fp8 hi-plane of x: 16,777,216 threads (grid 65536 x 256)
__global__ void prepack_x8_kernel(const float* __restrict__ x, u8* __restrict__ X8) {
  unsigned int idx = blockIdx.x * 256 + threadIdx.x;  // < 16,777,216
  int e  = idx & 7;
  int l  = (idx >> 3) & 63;
  int ks = (idx >> 9) & 31;
  int mt = (idx >> 14) & 3;
  int t  = idx >> 16;
  int m = mt * 16 + (l & 15);
  int k = ks * 32 + ((l >> 4) << 3) + e;
  int cc = k >> 9, kw = k & 511;
  float v = x[(((size_t)m * T_ + t) * 512 + kw) * 2 + cc];
  X8[idx] = f2fp8(v);
}

// 8,388,608 threads exactly (grid 32768 x 256): f16 hi + fp8 lo residual.
__global__ void prepack_w_kernel(const float* __restrict__ Wri, const float* __restrict__ Wii,
                                 const float* __restrict__ Wrh, const float* __restrict__ Wih,
                                 f16* __restrict__ hi, u8* __restrict__ lo8) {
  unsigned int idx = blockIdx.x * 256 + threadIdx.x;  // < 8,388,608
  int e  = idx & 7;
  int l  = (idx >> 3) & 63;
  int ks = (idx >> 9) & 63;
  int nt = (idx >> 15) & 1;
  int jb = idx >> 16;                 // 0..127
  int n_local = nt * 16 + (l & 15);
  int np = jb * 32 + n_local;
  int j  = np >> 3;
  int g  = (np >> 1) & 3;
  int cc = np & 1;
  int k  = ks * 32 + ((l >> 4) << 3) + e;
  int kb = k >> 9, kw = k & 511;
  size_t s = (size_t)(g * 512 + j) * 512 + kw;
  float v;
  if (cc == 0) v = (kb == 0) ? Wri[s] : (kb == 1) ? -Wii[s] : (kb == 2) ? Wrh[s] : -Wih[s];
  else         v = (kb == 0) ? Wii[s] : (kb == 1) ?  Wri[s] : (kb == 2) ? Wih[s] :  Wrh[s];
  f16 h = (f16)v;
  hi[idx] = h;
  lo8[idx] = f2fp8((v - (float)h) * SC);
}

struct PersistArgs {
  const f16* X0;      // [T][131072] layer-0 x frags
  const u8*  X8;      // [T][65536]  layer-0 x fp8 hi-plane
  f16* ys0;           // 16-slot ring: layer-0 h frags (= layer-1 x input)
  f16* h1;            // 16-slot ring: layer-1 h frags
  u8*  ys08;          // fp8 rings [16][65536]
  u8*  h18;
  const f16* Whi0;    // [128][65536] f16
  const f16* Whi1;
  const u8*  Wlo80;   // [128][65536] fp8
  const u8*  Wlo81;
  const float *br10, *bi10, *br20, *bi20;
  const float *br11, *bi11, *br21, *bi21;
  float* y;           // (B,T,512,2)
  float* hout;        // (2,B,512,2)
  float* cout;        // (2,B,512,2)
  unsigned* flags;    // [256]
};

// 256 blocks x 1024 threads; stage s: L0 computes step s, L1 computes s-1.
__global__ __launch_bounds__(1024, 4) void lstm_persist(PersistArgs a) {
  extern __shared__ char smem[];
  f16* Wl = (f16*)smem;                                  // W-hi slice 131072 B
  float* redf = (float*)(smem + 131072);                 // [2][4][2][16][17] f32
  volatile unsigned* goLds = (volatile unsigned*)(smem + 148480);

  int bid = blockIdx.x;
  int xcd = bid & 7, rr = bid >> 3;
  int lay = rr & 1;
  int jb = (rr >> 1) * 8 + xcd;       // 0..127
  int tid = threadIdx.x;
  int w = tid >> 6, l = tid & 63;
  int mt = w & 3, kq = w >> 2;
  int n_loc = l & 15, r0 = (l >> 4) * 4;

  // epilogue identity (tid < 256): one (m, j-local) pair
  int em = tid >> 2, ejl = tid & 3;
  int emt = em >> 4, eml = em & 15;
  int jg = jb * 4 + ejl;

  const f16* WhiG = (lay ? a.Whi1 : a.Whi0) + (size_t)jb * 65536;
  const u8*  Wlo8G = (lay ? a.Wlo81 : a.Wlo80) + (size_t)jb * 65536;
  for (int i = tid * 8; i < 65536; i += 8192)
    *reinterpret_cast<f16x8*>(Wl + i) = *reinterpret_cast<const f16x8*>(WhiG + i);
  if (tid == 0) *goLds = 0u;

  float bsr[4], bsi[4];
  {
    const float* br1 = lay ? a.br11 : a.br10;
    const float* bi1 = lay ? a.bi11 : a.bi10;
    const float* br2 = lay ? a.br21 : a.br20;
    const float* bi2 = lay ? a.bi21 : a.bi20;
#pragma unroll
    for (int g = 0; g < 4; ++g) {
      int nb = g * 512 + jg;
      bsr[g] = br1[nb] + br2[nb];
      bsi[g] = bi1[nb] + bi2[nb];
    }
  }
  __syncthreads();

  float c_r = 0.f, c_i = 0.f;

  for (int s = 0; s <= T_; ++s) {
    if (s > 0) {   // wait: all blocks published stage s-1
      if (w == 0) {
        const unsigned* fp = a.flags + l * 4;
        for (;;) {
          unsigned f0 = __hip_atomic_load(fp + 0, __ATOMIC_RELAXED, __HIP_MEMORY_SCOPE_AGENT);
          unsigned f1 = __hip_atomic_load(fp + 1, __ATOMIC_RELAXED, __HIP_MEMORY_SCOPE_AGENT);
          unsigned f2 = __hip_atomic_load(fp + 2, __ATOMIC_RELAXED, __HIP_MEMORY_SCOPE_AGENT);
          unsigned f3 = __hip_atomic_load(fp + 3, __ATOMIC_RELAXED, __HIP_MEMORY_SCOPE_AGENT);
          unsigned mn = min(min(f0, f1), min(f2, f3));
          if (__all(mn >= (unsigned)s)) break;
          __builtin_amdgcn_s_sleep(1);
        }
        if (l == 0) { asm volatile("" ::: "memory"); *goLds = (unsigned)s; }
      } else {
        while (*goLds < (unsigned)s) __builtin_amdgcn_s_sleep(1);
      }
      asm volatile("" ::: "memory");
    }

    bool active = lay ? (s >= 1) : (s < T_);
    int t = lay ? (s - 1) : s;

    f32x4 comb0 = {0.f, 0.f, 0.f, 0.f}, comb1 = {0.f, 0.f, 0.f, 0.f};
    int rb0 = 0, rb1 = 0;
    if (active) {
      f32x4 acc0 = {0,0,0,0}, acc1 = {0,0,0,0}, sacc0 = {0,0,0,0}, sacc1 = {0,0,0,0};
      bool hwave = (kq >= 2);
      if (!hwave || t > 0) {
        const f16* Ab; const u8* Ab8;
        if (!hwave) {
          Ab  = lay ? (a.ys0 + (size_t)(t & RMASK) * 131072) : (a.X0 + (size_t)t * 131072);
          Ab8 = lay ? (a.ys08 + (size_t)(t & RMASK) * 65536) : (a.X8 + (size_t)t * 65536);
        } else {
          Ab  = (lay ? a.h1  : a.ys0)  + (size_t)((t - 1) & RMASK) * 131072;
          Ab8 = (lay ? a.h18 : a.ys08) + (size_t)((t - 1) & RMASK) * 65536;
        }
        int ksl = (kq & 1) * 16;       // local ks within the x- or h-buffer
        int ksg = kq * 16;             // global ks 0..63 into W
        const f16* pa  = Ab + mt * 32768 + ksl * 1024 + l * 8;
        const u8*  pa8 = Ab8 + mt * 16384 + ksl * 512 + l * 8;
        const f16* pw  = Wl + ksg * 512 + l * 8;
        const u8*  po8 = Wlo8G + ksg * 512 + l * 8;
#pragma unroll 4
        for (int i = 0; i < 16; ++i) {
          f16x8 ah = *reinterpret_cast<const f16x8*>(pa + i * 1024);
          f16x8 al = *reinterpret_cast<const f16x8*>(pa + i * 1024 + 512);
          f16x8 w0 = *reinterpret_cast<const f16x8*>(pw + i * 512);
          f16x8 w1 = *reinterpret_cast<const f16x8*>(pw + 32768 + i * 512);
          long a8  = *reinterpret_cast<const long*>(pa8 + i * 512);
          long o0  = *reinterpret_cast<const long*>(po8 + i * 512);
          long o1  = *reinterpret_cast<const long*>(po8 + 32768 + i * 512);
          acc0 = MFMA(ah, w0, acc0); sacc0 = MFMA(al, w0, sacc0); sacc0 = MFMA8(a8, o0, sacc0);
          acc1 = MFMA(ah, w1, acc1); sacc1 = MFMA(al, w1, sacc1); sacc1 = MFMA8(a8, o1, sacc1);
        }
      }
      comb0 = acc0 + sacc0 * INV_SC;
      comb1 = acc1 + sacc1 * INV_SC;
      rb0 = (((kq >> 1) * 4 + mt) * 2 + 0) * 272 + n_loc * 17 + r0;
      rb1 = (((kq >> 1) * 4 + mt) * 2 + 1) * 272 + n_loc * 17 + r0;
      if ((kq & 1) == 0) {
#pragma unroll
        for (int q = 0; q < 4; ++q) { redf[rb0 + q] = comb0[q]; redf[rb1 + q] = comb1[q]; }
      }
    }
    __syncthreads();
    if (active && (kq & 1)) {
#pragma unroll
      for (int q = 0; q < 4; ++q) { redf[rb0 + q] += comb0[q]; redf[rb1 + q] += comb1[q]; }
    }
    __syncthreads();

    float hr = 0.f, him = 0.f, cnr = 0.f, cni = 0.f;
    if (active && tid < 256) {
      float zr[4], zi[4];
#pragma unroll
      for (int g = 0; g < 4; ++g) {
        int nl = ejl * 8 + g * 2;
        int nt_ = nl >> 4, nn = nl & 15;
        int i0 = (emt * 2 + nt_) * 272 + nn * 17 + eml;
        int i1 = ((4 + emt) * 2 + nt_) * 272 + nn * 17 + eml;
        zr[g] = redf[i0] + redf[i1] + bsr[g];
        zi[g] = redf[i0 + 17] + redf[i1 + 17] + bsi[g];
      }
      float gr[4], gi[4];
#pragma unroll
      for (int g = 0; g < 4; ++g) {
        float mag = sqrtf(zr[g] * zr[g] + zi[g] * zi[g]);
        float fn = (g < 3) ? (1.f / (1.f + __expf(-mag))) : tanhf(mag);
        float sg = fn / (mag + 1e-8f);
        gr[g] = zr[g] * sg;
        gi[g] = zi[g] * sg;
      }
      cnr = c_r * gr[1] + gr[0] * gr[3];
      cni = c_i * gi[1] + gi[0] * gi[3];
      c_r = cnr; c_i = cni;
      float mm = sqrtf(cnr * cnr + cni * cni);
      float sg = tanhf(mm) / (mm + 1e-8f);
      float dr = cnr * sg, di = cni * sg;
      hr  = gr[2] * dr - gi[2] * di;
      him = gi[2] * dr + gr[2] * di;

      // f16 h-frags pairwise (j, j^1): 2 u32 MALL stores per lane
      f16 h0 = (f16)hr, h2 = (f16)him;
      unsigned a1 = (unsigned)__builtin_bit_cast(unsigned short, h0)
                  | ((unsigned)__builtin_bit_cast(unsigned short, (f16)((hr - (float)h0) * SC)) << 16);
      unsigned a2 = (unsigned)__builtin_bit_cast(unsigned short, h2)
                  | ((unsigned)__builtin_bit_cast(unsigned short, (f16)((him - (float)h2) * SC)) << 16);
      unsigned b1 = __shfl_xor(a1, 1, 64);
      unsigned b2 = __shfl_xor(a2, 1, 64);
      unsigned v0, v1; int kbase;
      int p = ejl >> 1;
      if ((ejl & 1) == 0) {
        v0 = (a1 & 0xffffu) | (b1 << 16);
        v1 = (a1 >> 16) | (b1 & 0xffff0000u);
        kbase = jb * 4 + 2 * p;               // real planes
      } else {
        v0 = (b2 & 0xffffu) | (a2 << 16);
        v1 = (b2 >> 16) | (a2 & 0xffff0000u);
        kbase = 512 + jb * 4 + 2 * p;         // imag planes
      }
      f16* Yb = (lay ? a.h1 : a.ys0) + (size_t)(t & RMASK) * 131072;
      unsigned* Y32 = (unsigned*)Yb;
      int ks2 = kbase >> 5;
      int lane_h = eml + 16 * ((kbase >> 3) & 3);
      int e0 = kbase & 7;
      int idx0 = ((emt * 32 + ks2) * 2 + 0) * 512 + lane_h * 8 + e0;
      int idx1 = ((emt * 32 + ks2) * 2 + 1) * 512 + lane_h * 8 + e0;
      __hip_atomic_store(&Y32[idx0 >> 1], v0, __ATOMIC_RELAXED, __HIP_MEMORY_SCOPE_AGENT);
      __hip_atomic_store(&Y32[idx1 >> 1], v1, __ATOMIC_RELAXED, __HIP_MEMORY_SCOPE_AGENT);

      // fp8 hi-plane of h: quad shfl-OR packs 4 j-bytes into one u32
      unsigned wr8 = ((unsigned)f2fp8(hr))  << (8 * ejl);
      unsigned wi8 = ((unsigned)f2fp8(him)) << (8 * ejl);
      wr8 |= __shfl_xor(wr8, 1, 64); wr8 |= __shfl_xor(wr8, 2, 64);
      wi8 |= __shfl_xor(wi8, 1, 64); wi8 |= __shfl_xor(wi8, 2, 64);
      u8* Yb8 = (lay ? a.h18 : a.ys08) + (size_t)(t & RMASK) * 65536;
      unsigned* Y832 = (unsigned*)Yb8;
      int lane_r = eml + 16 * ((jb >> 1) & 3);
      int e08 = (jb & 1) * 4;
      int ksr8 = jb >> 3;
      if (ejl == 0) {
        int b = (((emt * 32 + ksr8) * 64 + lane_r) * 8 + e08) >> 2;
        __hip_atomic_store(&Y832[b], wr8, __ATOMIC_RELAXED, __HIP_MEMORY_SCOPE_AGENT);
      } else if (ejl == 1) {
        int b = (((emt * 32 + 16 + ksr8) * 64 + lane_r) * 8 + e08) >> 2;
        __hip_atomic_store(&Y832[b], wi8, __ATOMIC_RELAXED, __HIP_MEMORY_SCOPE_AGENT);
      }
    }

    asm volatile("s_waitcnt vmcnt(0)" ::: "memory");   // drain h-stores (per-wave)
    __syncthreads();
    if (tid == 0 && s < T_)
      __hip_atomic_store(&a.flags[bid], (unsigned)(s + 1),
                         __ATOMIC_RELAXED, __HIP_MEMORY_SCOPE_AGENT);

    // deferred fp32 outputs — off the flag path, drain during next poll
    if (active && tid < 256) {
      if (lay) {
        float2 yv; yv.x = hr; yv.y = him;
        *reinterpret_cast<float2*>(a.y + (((size_t)em * T_ + t) * 512 + jg) * 2) = yv;
      }
      if (t == T_ - 1) {
        float* hp = a.hout + (size_t)lay * 65536 + ((size_t)em * 512 + jg) * 2;
        hp[0] = hr; hp[1] = him;
        float* cq = a.cout + (size_t)lay * 65536 + ((size_t)em * 512 + jg) * 2;
        cq[0] = cnr; cq[1] = cni;
      }
    }
  }
}

extern "C" void kernel_launch(void* const* d_in, const int* in_sizes, int n_in,
                              void* d_out, int out_size, void* d_ws, size_t ws_size,
                              hipStream_t stream) {
  const float* x = (const float*)d_in[0];
  char* ws = (char*)d_ws;
  f16* X0    = (f16*)(ws + 0);                         //  64 MB
  u8*  X8    = (u8*) (ws + (size_t)67108864);          //  16 MB
  f16* Whi0  = (f16*)(ws + (size_t)83886080);          //  16 MB
  f16* Whi1  = (f16*)(ws + (size_t)100663296);         //  16 MB
  u8*  Wlo80 = (u8*) (ws + (size_t)117440512);         //   8 MB
  u8*  Wlo81 = (u8*) (ws + (size_t)125829120);         //   8 MB
  f16* ys0   = (f16*)(ws + (size_t)134217728);         //   4 MB ring
  f16* h1    = (f16*)(ws + (size_t)138412032);         //   4 MB ring
  u8*  ys08  = (u8*) (ws + (size_t)142606336);         //   1 MB ring
  u8*  h18   = (u8*) (ws + (size_t)143654912);         //   1 MB ring
  unsigned* flags = (unsigned*)(ws + (size_t)144703488);  // 1 KB

  hipMemsetAsync(ws + 144703488, 0, 1024, stream);

  prepack_x_kernel<<<131072, 256, 0, stream>>>(x, X0);
  prepack_x8_kernel<<<65536, 256, 0, stream>>>(x, X8);
  prepack_w_kernel<<<32768, 256, 0, stream>>>((const float*)d_in[1], (const float*)d_in[2],
                                              (const float*)d_in[5], (const float*)d_in[6],
                                              Whi0, Wlo80);
  prepack_w_kernel<<<32768, 256, 0, stream>>>((const float*)d_in[9], (const float*)d_in[10],
                                              (const float*)d_in[13], (const float*)d_in[14],
                                              Whi1, Wlo81);

  float* y = (float*)d_out;
  PersistArgs pa;
  pa.X0 = X0; pa.X8 = X8; pa.ys0 = ys0; pa.h1 = h1; pa.ys08 = ys08; pa.h18 = h18;
  pa.Whi0 = Whi0; pa.Whi1 = Whi1; pa.Wlo80 = Wlo80; pa.Wlo81 = Wlo81;
  pa.br10 = (const float*)d_in[3];  pa.bi10 = (const float*)d_in[4];
  pa.br20 = (const float*)d_in[7];  pa.bi20 = (const float*)d_in[8];
  pa.br11 = (const float*)d_in[11]; pa.bi11 = (const float*)d_in[12];
  pa.br21 = (const float*)d_in[15]; pa.bi21 = (const float*)d_in[16];
  pa.y = y; pa.hout = y + 16777216; pa.cout = y + 16777216 + 131072;
  pa.flags = flags;

  hipFuncSetAttribute((const void*)lstm_persist,
                      hipFuncAttributeMaxDynamicSharedMemorySize, 148608);
  void* kargs[] = { &pa };
  hipLaunchCooperativeKernel((const void*)lstm_persist, dim3(256), dim3(1024),
                             kargs, 148608, stream);
}

// Round 14
// 3984.930 us; speedup vs baseline: 2.5685x; 1.1381x over previous
//
#include <hip/hip_runtime.h>
#include <hip/hip_bf16.h>

typedef _Float16 f16;
typedef _Float16 f16x8 __attribute__((ext_vector_type(8)));
typedef float f32x4 __attribute__((ext_vector_type(4)));

#define T_ 256
#define SC 2048.0f
#define INV_SC (1.0f / 2048.0f)
#define RMASK 15          // 16-slot rings for recurrent h buffers
#define NSTAGE 258        // L1 runs at skew 2
#define MFMA(A, B, C)  __builtin_amdgcn_mfma_f32_16x16x32_f16(A, B, C, 0, 0, 0)

// ---------------------------------------------------------------------------
// Numerics = round 8 EXACT (absmax 0.0039): f16-hi GEMM + f16 a_lo + f16 W_lo
// compensation, fp32 cell state in registers.
// Dataflow = round 13: x-half GEMM carried in registers (prefetched for stage
// s+1 by waves kq>=2 after flag publication; L1 at skew-2 so its x input
// exists a stage early); h-half split across ALL 16 waves (8 ks each).
// Sync = round 11 EXACT (proven): wave-0 poll -> goLds, two redf barriers,
// block-wide vmcnt(0) + __syncthreads + tid0 flag.
//   A-buffers (x or h frags): [mt 4][ks 32][part 2][lane 64][e 8] f16
//   W pack per layer: [which 2 (hi/lo*SC)][jb 128][nt 2][ks 64][lane 64][e 8]
// ---------------------------------------------------------------------------

__global__ void prepack_x_kernel(const float* __restrict__ x, f16* __restrict__ X0) {
  unsigned int idx = blockIdx.x * 256 + threadIdx.x;  // < 33,554,432
  int e    = idx & 7;
  int l    = (idx >> 3) & 63;
  int part = (idx >> 9) & 1;
  int ks   = (idx >> 10) & 31;
  int mt   = (idx >> 15) & 3;
  int t    = idx >> 17;
  int m = mt * 16 + (l & 15);
  int k = ks * 32 + ((l >> 4) << 3) + e;
  int cc = k >> 9, kw = k & 511;
  float v = x[(((size_t)m * T_ + t) * 512 + kw) * 2 + cc];
  f16 h = (f16)v;
  X0[idx] = part ? (f16)((v - (float)h) * SC) : h;
}

// 16,777,216 threads exactly (grid 65536 x 256): hi plane + lo plane (both f16).
__global__ void prepack_w_kernel(const float* __restrict__ Wri, const float* __restrict__ Wii,
                                 const float* __restrict__ Wrh, const float* __restrict__ Wih,
                                 f16* __restrict__ out) {
  unsigned int idx = blockIdx.x * 256 + threadIdx.x;  // < 16,777,216
  int e     = idx & 7;
  int l     = (idx >> 3) & 63;
  int ks    = (idx >> 9) & 63;
  int nt    = (idx >> 15) & 1;
  int jb    = (idx >> 16) & 127;
  int which = idx >> 23;
  int n_local = nt * 16 + (l & 15);
  int np = jb * 32 + n_local;
  int j  = np >> 3;
  int g  = (np >> 1) & 3;
  int cc = np & 1;
  int k  = ks * 32 + ((l >> 4) << 3) + e;
  int kb = k >> 9, kw = k & 511;
  size_t s = (size_t)(g * 512 + j) * 512 + kw;
  float v;
  if (cc == 0) v = (kb == 0) ? Wri[s] : (kb == 1) ? -Wii[s] : (kb == 2) ? Wrh[s] : -Wih[s];
  else         v = (kb == 0) ? Wii[s] : (kb == 1) ?  Wri[s] : (kb == 2) ? Wih[s] :  Wrh[s];
  f16 h = (f16)v;
  out[idx] = which ? (f16)((v - (float)h) * SC) : h;
}

struct PersistArgs {
  const f16* X0;      // [T][131072] layer-0 x frags
  f16* ys0;           // 16-slot ring: layer-0 h frags (= layer-1 x input)
  f16* h1;            // 16-slot ring: layer-1 h frags
  const f16* Wpk0;    // [2][128][65536] (hi | lo)
  const f16* Wpk1;
  const float *br10, *bi10, *br20, *bi20;
  const float *br11, *bi11, *br21, *bi21;
  float* y;           // (B,T,512,2)
  float* hout;        // (2,B,512,2)
  float* cout;        // (2,B,512,2)
  unsigned* flags;    // [256]
};

// 256 blocks x 1024 threads; stage s: L0 computes step s, L1 computes s-2.
__global__ __launch_bounds__(1024, 4) void lstm_persist(PersistArgs a) {
  extern __shared__ char smem[];
  f16* Wl = (f16*)smem;                                  // W-hi slice 131072 B
  float* redf = (float*)(smem + 131072);                 // [2][4][2][16][17] f32
  volatile unsigned* goLds = (volatile unsigned*)(smem + 148480);

  int bid = blockIdx.x;
  int xcd = bid & 7, rr = bid >> 3;
  int lay = rr & 1;
  int jb = (rr >> 1) * 8 + xcd;       // 0..127
  int tid = threadIdx.x;
  int w = tid >> 6, l = tid & 63;
  int mt = w & 3, kq = w >> 2;
  int n_loc = l & 15, r0 = (l >> 4) * 4;
  bool carrier = (kq >= 2);

  // epilogue identity (tid < 256): one (m, j-local) pair
  int em = tid >> 2, ejl = tid & 3;
  int emt = em >> 4, eml = em & 15;
  int jg = jb * 4 + ejl;

  const f16* Wpk = lay ? a.Wpk1 : a.Wpk0;
  const f16* WhiG = Wpk + (size_t)jb * 65536;
  const f16* WloG = Wpk + 8388608 + (size_t)jb * 65536;
  for (int i = tid * 8; i < 65536; i += 8192)
    *reinterpret_cast<f16x8*>(Wl + i) = *reinterpret_cast<const f16x8*>(WhiG + i);
  if (tid == 0) *goLds = 0u;

  float bsr[4], bsi[4];
  {
    const float* br1 = lay ? a.br11 : a.br10;
    const float* bi1 = lay ? a.bi11 : a.bi10;
    const float* br2 = lay ? a.br21 : a.br20;
    const float* bi2 = lay ? a.bi21 : a.bi20;
#pragma unroll
    for (int g = 0; g < 4; ++g) {
      int nb = g * 512 + jg;
      bsr[g] = br1[nb] + br2[nb];
      bsi[g] = bi1[nb] + bi2[nb];
    }
  }
  __syncthreads();

  const f32x4 z4 = {0.f, 0.f, 0.f, 0.f};
  f32x4 xm0 = z4, xs0 = z4, xm1 = z4, xs1 = z4;   // carried x-GEMM partials

  // prime: L0 carriers compute x-GEMM for t=0 (X0 static, no dependency)
  if (carrier && lay == 0) {
    int ksl = (kq - 2) * 16;
    const f16* pa = a.X0 + mt * 32768 + ksl * 1024 + l * 8;
    const f16* pw = Wl + ksl * 512 + l * 8;
    const f16* po = WloG + ksl * 512 + l * 8;
#pragma unroll 4
    for (int i = 0; i < 16; ++i) {
      f16x8 ah = *reinterpret_cast<const f16x8*>(pa + i * 1024);
      f16x8 al = *reinterpret_cast<const f16x8*>(pa + i * 1024 + 512);
      f16x8 w0 = *reinterpret_cast<const f16x8*>(pw + i * 512);
      f16x8 w1 = *reinterpret_cast<const f16x8*>(pw + 32768 + i * 512);
      f16x8 o0 = *reinterpret_cast<const f16x8*>(po + i * 512);
      f16x8 o1 = *reinterpret_cast<const f16x8*>(po + 32768 + i * 512);
      xm0 = MFMA(ah, w0, xm0); xs0 = MFMA(al, w0, xs0); xs0 = MFMA(ah, o0, xs0);
      xm1 = MFMA(ah, w1, xm1); xs1 = MFMA(al, w1, xs1); xs1 = MFMA(ah, o1, xs1);
    }
  }

  float c_r = 0.f, c_i = 0.f;

  for (int s = 0; s < NSTAGE; ++s) {
    bool active = lay ? (s >= 2) : (s < T_);
    int t = lay ? (s - 2) : s;

    if (s > 0) {   // wait: all blocks published stage s-1  (round-11 skeleton)
      if (w == 0) {
        const unsigned* fp = a.flags + l * 4;
        for (;;) {
          unsigned f0 = __hip_atomic_load(fp + 0, __ATOMIC_RELAXED, __HIP_MEMORY_SCOPE_AGENT);
          unsigned f1 = __hip_atomic_load(fp + 1, __ATOMIC_RELAXED, __HIP_MEMORY_SCOPE_AGENT);
          unsigned f2 = __hip_atomic_load(fp + 2, __ATOMIC_RELAXED, __HIP_MEMORY_SCOPE_AGENT);
          unsigned f3 = __hip_atomic_load(fp + 3, __ATOMIC_RELAXED, __HIP_MEMORY_SCOPE_AGENT);
          unsigned mn = min(min(f0, f1), min(f2, f3));
          if (__all(mn >= (unsigned)s)) break;
          __builtin_amdgcn_s_sleep(1);
        }
        if (l == 0) { asm volatile("" ::: "memory"); *goLds = (unsigned)s; }
      } else {
        while (*goLds < (unsigned)s) __builtin_amdgcn_s_sleep(1);
      }
      asm volatile("" ::: "memory");
    }

    // ---- h-half GEMM (8 ks per wave) on top of carried x partials ----
    f32x4 comb0 = z4, comb1 = z4;
    int rb0 = 0, rb1 = 0;
    if (active) {
      f32x4 acc0  = carrier ? xm0 : z4;
      f32x4 sacc0 = carrier ? xs0 : z4;
      f32x4 acc1  = carrier ? xm1 : z4;
      f32x4 sacc1 = carrier ? xs1 : z4;
      if (t > 0) {
        const f16* Ab = (lay ? a.h1 : a.ys0) + (size_t)((t - 1) & RMASK) * 131072;
        int ksl = kq * 8;              // h-buffer local ks
        int ksg = 32 + kq * 8;         // W global ks
        const f16* pa = Ab + mt * 32768 + ksl * 1024 + l * 8;
        const f16* pw = Wl + ksg * 512 + l * 8;
        const f16* po = WloG + ksg * 512 + l * 8;
#pragma unroll
        for (int i = 0; i < 8; ++i) {
          f16x8 ah = *reinterpret_cast<const f16x8*>(pa + i * 1024);
          f16x8 al = *reinterpret_cast<const f16x8*>(pa + i * 1024 + 512);
          f16x8 w0 = *reinterpret_cast<const f16x8*>(pw + i * 512);
          f16x8 w1 = *reinterpret_cast<const f16x8*>(pw + 32768 + i * 512);
          f16x8 o0 = *reinterpret_cast<const f16x8*>(po + i * 512);
          f16x8 o1 = *reinterpret_cast<const f16x8*>(po + 32768 + i * 512);
          acc0 = MFMA(ah, w0, acc0); sacc0 = MFMA(al, w0, sacc0); sacc0 = MFMA(ah, o0, sacc0);
          acc1 = MFMA(ah, w1, acc1); sacc1 = MFMA(al, w1, sacc1); sacc1 = MFMA(ah, o1, sacc1);
        }
      }
      comb0 = acc0 + sacc0 * INV_SC;
      comb1 = acc1 + sacc1 * INV_SC;
      rb0 = (((kq >> 1) * 4 + mt) * 2 + 0) * 272 + n_loc * 17 + r0;
      rb1 = (((kq >> 1) * 4 + mt) * 2 + 1) * 272 + n_loc * 17 + r0;
      if ((kq & 1) == 0) {
#pragma unroll
        for (int q = 0; q < 4; ++q) { redf[rb0 + q] = comb0[q]; redf[rb1 + q] = comb1[q]; }
      }
    }
    __syncthreads();
    if (active && (kq & 1)) {
#pragma unroll
      for (int q = 0; q < 4; ++q) { redf[rb0 + q] += comb0[q]; redf[rb1 + q] += comb1[q]; }
    }
    __syncthreads();

    float hr = 0.f, him = 0.f, cnr = 0.f, cni = 0.f;
    if (active && tid < 256) {
      float zr[4], zi[4];
#pragma unroll
      for (int g = 0; g < 4; ++g) {
        int nl = ejl * 8 + g * 2;
        int nt_ = nl >> 4, nn = nl & 15;
        int i0 = (emt * 2 + nt_) * 272 + nn * 17 + eml;
        int i1 = ((4 + emt) * 2 + nt_) * 272 + nn * 17 + eml;
        zr[g] = redf[i0] + redf[i1] + bsr[g];
        zi[g] = redf[i0 + 17] + redf[i1 + 17] + bsi[g];
      }
      float gr[4], gi[4];
#pragma unroll
      for (int g = 0; g < 4; ++g) {
        float mag = sqrtf(zr[g] * zr[g] + zi[g] * zi[g]);
        float fn = (g < 3) ? (1.f / (1.f + __expf(-mag))) : tanhf(mag);
        float sg = fn / (mag + 1e-8f);
        gr[g] = zr[g] * sg;
        gi[g] = zi[g] * sg;
      }
      cnr = c_r * gr[1] + gr[0] * gr[3];
      cni = c_i * gi[1] + gi[0] * gi[3];
      c_r = cnr; c_i = cni;
      float mm = sqrtf(cnr * cnr + cni * cni);
      float sg = tanhf(mm) / (mm + 1e-8f);
      float dr = cnr * sg, di = cni * sg;
      hr  = gr[2] * dr - gi[2] * di;
      him = gi[2] * dr + gr[2] * di;

      // f16 h-frags pairwise (j, j^1): 2 u32 MALL stores per lane
      f16 h0 = (f16)hr, h2 = (f16)him;
      unsigned a1 = (unsigned)__builtin_bit_cast(unsigned short, h0)
                  | ((unsigned)__builtin_bit_cast(unsigned short, (f16)((hr - (float)h0) * SC)) << 16);
      unsigned a2 = (unsigned)__builtin_bit_cast(unsigned short, h2)
                  | ((unsigned)__builtin_bit_cast(unsigned short, (f16)((him - (float)h2) * SC)) << 16);
      unsigned b1 = __shfl_xor(a1, 1, 64);
      unsigned b2 = __shfl_xor(a2, 1, 64);
      unsigned v0, v1; int kbase;
      int p = ejl >> 1;
      if ((ejl & 1) == 0) {
        v0 = (a1 & 0xffffu) | (b1 << 16);
        v1 = (a1 >> 16) | (b1 & 0xffff0000u);
        kbase = jb * 4 + 2 * p;               // real planes
      } else {
        v0 = (b2 & 0xffffu) | (a2 << 16);
        v1 = (b2 >> 16) | (a2 & 0xffff0000u);
        kbase = 512 + jb * 4 + 2 * p;         // imag planes
      }
      f16* Yb = (lay ? a.h1 : a.ys0) + (size_t)(t & RMASK) * 131072;
      unsigned* Y32 = (unsigned*)Yb;
      int ks2 = kbase >> 5;
      int lane_h = eml + 16 * ((kbase >> 3) & 3);
      int e0 = kbase & 7;
      int idx0 = ((emt * 32 + ks2) * 2 + 0) * 512 + lane_h * 8 + e0;
      int idx1 = ((emt * 32 + ks2) * 2 + 1) * 512 + lane_h * 8 + e0;
      __hip_atomic_store(&Y32[idx0 >> 1], v0, __ATOMIC_RELAXED, __HIP_MEMORY_SCOPE_AGENT);
      __hip_atomic_store(&Y32[idx1 >> 1], v1, __ATOMIC_RELAXED, __HIP_MEMORY_SCOPE_AGENT);
    }

    asm volatile("s_waitcnt vmcnt(0)" ::: "memory");   // drain h-stores (per-wave)
    __syncthreads();
    if (tid == 0 && s + 1 < NSTAGE)
      __hip_atomic_store(&a.flags[bid], (unsigned)(s + 1),
                         __ATOMIC_RELAXED, __HIP_MEMORY_SCOPE_AGENT);

    // ---- carrier x-prefetch for stage s+1 (overlaps inter-block poll) ----
    if (carrier) {
      xm0 = z4; xs0 = z4; xm1 = z4; xs1 = z4;
      bool nextAct = lay ? (s + 1 >= 2 && s + 1 < NSTAGE) : (s + 1 < T_);
      if (nextAct) {
        int tn = lay ? (s - 1) : (s + 1);   // next stage's step
        const f16* Ab = lay ? (a.ys0 + (size_t)(tn & RMASK) * 131072)
                            : (a.X0 + (size_t)tn * 131072);
        int ksl = (kq - 2) * 16;
        const f16* pa = Ab + mt * 32768 + ksl * 1024 + l * 8;
        const f16* pw = Wl + ksl * 512 + l * 8;
        const f16* po = WloG + ksl * 512 + l * 8;
#pragma unroll 4
        for (int i = 0; i < 16; ++i) {
          f16x8 ah = *reinterpret_cast<const f16x8*>(pa + i * 1024);
          f16x8 al = *reinterpret_cast<const f16x8*>(pa + i * 1024 + 512);
          f16x8 w0 = *reinterpret_cast<const f16x8*>(pw + i * 512);
          f16x8 w1 = *reinterpret_cast<const f16x8*>(pw + 32768 + i * 512);
          f16x8 o0 = *reinterpret_cast<const f16x8*>(po + i * 512);
          f16x8 o1 = *reinterpret_cast<const f16x8*>(po + 32768 + i * 512);
          xm0 = MFMA(ah, w0, xm0); xs0 = MFMA(al, w0, xs0); xs0 = MFMA(ah, o0, xs0);
          xm1 = MFMA(ah, w1, xm1); xs1 = MFMA(al, w1, xs1); xs1 = MFMA(ah, o1, xs1);
        }
      }
    }

    // deferred fp32 outputs — off the flag path
    if (active && tid < 256) {
      if (lay) {
        float2 yv; yv.x = hr; yv.y = him;
        *reinterpret_cast<float2*>(a.y + (((size_t)em * T_ + t) * 512 + jg) * 2) = yv;
      }
      if (t == T_ - 1) {
        float* hp = a.hout + (size_t)lay * 65536 + ((size_t)em * 512 + jg) * 2;
        hp[0] = hr; hp[1] = him;
        float* cq = a.cout + (size_t)lay * 65536 + ((size_t)em * 512 + jg) * 2;
        cq[0] = cnr; cq[1] = cni;
      }
    }
  }
}

extern "C" void kernel_launch(void* const* d_in, const int* in_sizes, int n_in,
                              void* d_out, int out_size, void* d_ws, size_t ws_size,
                              hipStream_t stream) {
  const float* x = (const float*)d_in[0];
  char* ws = (char*)d_ws;
  f16* X0   = (f16*)(ws + 0);                          //  64 MB
  f16* Wpk0 = (f16*)(ws + (size_t)67108864);           //  32 MB (hi|lo)
  f16* Wpk1 = (f16*)(ws + (size_t)100663296);          //  32 MB
  f16* ys0  = (f16*)(ws + (size_t)134217728);          //   4 MB ring
  f16* h1   = (f16*)(ws + (size_t)138412032);          //   4 MB ring
  unsigned* flags = (unsigned*)(ws + (size_t)142606336);  // 1 KB

  hipMemsetAsync(ws + 142606336, 0, 1024, stream);

  prepack_x_kernel<<<131072, 256, 0, stream>>>(x, X0);
  prepack_w_kernel<<<65536, 256, 0, stream>>>((const float*)d_in[1], (const float*)d_in[2],
                                              (const float*)d_in[5], (const float*)d_in[6], Wpk0);
  prepack_w_kernel<<<65536, 256, 0, stream>>>((const float*)d_in[9], (const float*)d_in[10],
                                              (const float*)d_in[13], (const float*)d_in[14], Wpk1);

  float* y = (float*)d_out;
  PersistArgs pa;
  pa.X0 = X0; pa.ys0 = ys0; pa.h1 = h1;
  pa.Wpk0 = Wpk0; pa.Wpk1 = Wpk1;
  pa.br10 = (const float*)d_in[3];  pa.bi10 = (const float*)d_in[4];
  pa.br20 = (const float*)d_in[7];  pa.bi20 = (const float*)d_in[8];
  pa.br11 = (const float*)d_in[11]; pa.bi11 = (const float*)d_in[12];
  pa.br21 = (const float*)d_in[15]; pa.bi21 = (const float*)d_in[16];
  pa.y = y; pa.hout = y + 16777216; pa.cout = y + 16777216 + 131072;
  pa.flags = flags;

  hipFuncSetAttribute((const void*)lstm_persist,
                      hipFuncAttributeMaxDynamicSharedMemorySize, 148608);
  void* kargs[] = { &pa };
  hipLaunchCooperativeKernel((const void*)lstm_persist, dim3(256), dim3(1024),
                             kargs, 148608, stream);
}